// Round 5
// baseline (21256.081 us; speedup 1.0000x reference)
//
#include <hip/hip_runtime.h>
#include <cstddef>
#include <cstdint>

constexpr int N_NODES = 16384;
constexpr int D_MODEL = 512;
constexpr int C_OUT   = 40;
constexpr int CW      = 256;                 // channel chunk width
constexpr int ND      = N_NODES * D_MODEL;   // per-timestep elements (512-ch)
constexpr int M2      = 2 * N_NODES;         // T*N rows

// ===========================================================================
// GEMM (bit A): C[M,Nc] = spikes(bits)[M,K] @ B[K,ldb] cols [colOff,colOff+Nc)
// double accumulate, output TC (double chunks, or float for the head GEMM).
// 64x64 tile, 256 thr, 4x4 micro, K-tile 16.
// ===========================================================================
template <typename TC>
__global__ __launch_bounds__(256)
void gemm_bits(const uint32_t* __restrict__ Abits, int ldaWords,
               const float* __restrict__ B, int ldb, int colOff,
               const float* __restrict__ bias,
               TC* __restrict__ C, int ldc, int M, int Nc, int K) {
    __shared__ double As[16][64];
    __shared__ double Bs[16][64];
    const int tid = threadIdx.x;
    const int tx  = tid & 15, ty = tid >> 4;
    const int row0 = blockIdx.y * 64 + ty * 4;
    const int col0 = blockIdx.x * 64 + tx * 4;
    const int ar = tid >> 2, ak = (tid & 3) * 4;
    const int bk = tid >> 4, bn = (tid & 15) * 4;
    const int gm = blockIdx.y * 64 + ar;

    double acc[4][4];
#pragma unroll
    for (int i = 0; i < 4; i++)
#pragma unroll
        for (int j = 0; j < 4; j++) acc[i][j] = 0.0;

    for (int k0 = 0; k0 < K; k0 += 16) {
        uint32_t w = 0;
        if (gm < M) w = Abits[(size_t)gm * ldaWords + ((k0 + ak) >> 5)];
        const int sh = (k0 + ak) & 31;
#pragma unroll
        for (int j = 0; j < 4; j++)
            As[ak + j][ar] = (double)((w >> (sh + j)) & 1u);
#pragma unroll
        for (int j = 0; j < 4; j++) {
            int gn = blockIdx.x * 64 + bn + j;
            Bs[bk][bn + j] = (gn < Nc) ? (double)B[(size_t)(k0 + bk) * ldb + colOff + gn] : 0.0;
        }
        __syncthreads();
#pragma unroll
        for (int kk = 0; kk < 16; kk++) {
            double a4[4], b4[4];
#pragma unroll
            for (int i = 0; i < 4; i++) a4[i] = As[kk][ty * 4 + i];
#pragma unroll
            for (int j = 0; j < 4; j++) b4[j] = Bs[kk][tx * 4 + j];
#pragma unroll
            for (int i = 0; i < 4; i++)
#pragma unroll
                for (int j = 0; j < 4; j++) acc[i][j] = fma(a4[i], b4[j], acc[i][j]);
        }
        __syncthreads();
    }
#pragma unroll
    for (int i = 0; i < 4; i++) {
        int r = row0 + i;
        if (r >= M) continue;
#pragma unroll
        for (int j = 0; j < 4; j++) {
            int c = col0 + j;
            if (c < Nc) {
                double v = acc[i][j];
                if (bias) v += (double)bias[c];
                C[(size_t)r * ldc + c] = (TC)v;
            }
        }
    }
}

// GEMM (float A, double out) — fc0 only.
__global__ __launch_bounds__(256)
void gemm_f32d(const float* __restrict__ A, int lda,
               const float* __restrict__ B, int ldb,
               const float* __restrict__ bias,
               double* __restrict__ C, int ldc, int M, int Nc, int K) {
    __shared__ double As[16][64];
    __shared__ double Bs[16][64];
    const int tid = threadIdx.x;
    const int tx  = tid & 15, ty = tid >> 4;
    const int row0 = blockIdx.y * 64 + ty * 4;
    const int col0 = blockIdx.x * 64 + tx * 4;
    const int ar = tid >> 2, ak = (tid & 3) * 4;
    const int bk = tid >> 4, bn = (tid & 15) * 4;
    const int gm = blockIdx.y * 64 + ar;
    double acc[4][4];
#pragma unroll
    for (int i = 0; i < 4; i++)
#pragma unroll
        for (int j = 0; j < 4; j++) acc[i][j] = 0.0;
    for (int k0 = 0; k0 < K; k0 += 16) {
#pragma unroll
        for (int j = 0; j < 4; j++)
            As[ak + j][ar] = (gm < M) ? (double)A[(size_t)gm * lda + k0 + ak + j] : 0.0;
#pragma unroll
        for (int j = 0; j < 4; j++) {
            int gn = blockIdx.x * 64 + bn + j;
            Bs[bk][bn + j] = (gn < Nc) ? (double)B[(size_t)(k0 + bk) * ldb + gn] : 0.0;
        }
        __syncthreads();
#pragma unroll
        for (int kk = 0; kk < 16; kk++) {
            double a4[4], b4[4];
#pragma unroll
            for (int i = 0; i < 4; i++) a4[i] = As[kk][ty * 4 + i];
#pragma unroll
            for (int j = 0; j < 4; j++) b4[j] = Bs[kk][tx * 4 + j];
#pragma unroll
            for (int i = 0; i < 4; i++)
#pragma unroll
                for (int j = 0; j < 4; j++) acc[i][j] = fma(a4[i], b4[j], acc[i][j]);
        }
        __syncthreads();
    }
#pragma unroll
    for (int i = 0; i < 4; i++) {
        int r = row0 + i;
        if (r >= M) continue;
#pragma unroll
        for (int j = 0; j < 4; j++) {
            int c = col0 + j;
            if (c < Nc) {
                double v = acc[i][j];
                if (bias) v += (double)bias[c];
                C[(size_t)r * ldc + c] = v;
            }
        }
    }
}

// GEMM (float A/B/C, double acc) — GNN branch (no thresholds downstream).
__global__ __launch_bounds__(256)
void gemm_f32(const float* __restrict__ A, int lda,
              const float* __restrict__ B, int ldb,
              const float* __restrict__ bias,
              float* __restrict__ C, int ldc, int M, int Nc, int K) {
    __shared__ float As[16][64];
    __shared__ float Bs[16][64];
    const int tid = threadIdx.x;
    const int tx  = tid & 15, ty = tid >> 4;
    const int row0 = blockIdx.y * 64 + ty * 4;
    const int col0 = blockIdx.x * 64 + tx * 4;
    const int ar = tid >> 2, ak = (tid & 3) * 4;
    const int bk = tid >> 4, bn = (tid & 15) * 4;
    const int gm = blockIdx.y * 64 + ar;
    double acc[4][4];
#pragma unroll
    for (int i = 0; i < 4; i++)
#pragma unroll
        for (int j = 0; j < 4; j++) acc[i][j] = 0.0;
    for (int k0 = 0; k0 < K; k0 += 16) {
#pragma unroll
        for (int j = 0; j < 4; j++) {
            int kk = k0 + ak + j;
            As[ak + j][ar] = (gm < M && kk < K) ? A[(size_t)gm * lda + kk] : 0.f;
        }
#pragma unroll
        for (int j = 0; j < 4; j++) {
            int gn = blockIdx.x * 64 + bn + j;
            int kk = k0 + bk;
            Bs[bk][bn + j] = (gn < Nc && kk < K) ? B[(size_t)kk * ldb + gn] : 0.f;
        }
        __syncthreads();
#pragma unroll
        for (int kk = 0; kk < 16; kk++) {
            float a4[4], b4[4];
#pragma unroll
            for (int i = 0; i < 4; i++) a4[i] = As[kk][ty * 4 + i];
#pragma unroll
            for (int j = 0; j < 4; j++) b4[j] = Bs[kk][tx * 4 + j];
#pragma unroll
            for (int i = 0; i < 4; i++)
#pragma unroll
                for (int j = 0; j < 4; j++) acc[i][j] = fma((double)a4[i], (double)b4[j], acc[i][j]);
        }
        __syncthreads();
    }
#pragma unroll
    for (int i = 0; i < 4; i++) {
        int r = row0 + i;
        if (r >= M) continue;
#pragma unroll
        for (int j = 0; j < 4; j++) {
            int c = col0 + j;
            if (c < Nc) {
                double v = acc[i][j];
                if (bias) v += (double)bias[c];
                C[(size_t)r * ldc + c] = (float)v;
            }
        }
    }
}

// ===========================================================================
// BN stats (double), finalize to double scale/shift
// ===========================================================================
template <typename T>
__global__ __launch_bounds__(256)
void col_stats(const T* __restrict__ X, int M, int Ch, int rowsPerBlock,
               double* __restrict__ sum, double* __restrict__ sumsq) {
    const int cl = threadIdx.x & 63;
    const int c  = blockIdx.x * 64 + cl;
    const int rg = threadIdx.x >> 6;
    const int r0 = blockIdx.y * rowsPerBlock;
    const int r1 = min(r0 + rowsPerBlock, M);
    double s = 0.0, q = 0.0;
    if (c < Ch) {
        for (int r = r0 + rg; r < r1; r += 4) {
            double v = (double)X[(size_t)r * Ch + c];
            s += v; q += v * v;
        }
    }
    __shared__ double ls[4][64], lq[4][64];
    ls[rg][cl] = s; lq[rg][cl] = q;
    __syncthreads();
    if (rg == 0 && c < Ch) {
        s = ls[0][cl] + ls[1][cl] + ls[2][cl] + ls[3][cl];
        q = lq[0][cl] + lq[1][cl] + lq[2][cl] + lq[3][cl];
        atomicAdd(&sum[c], s);
        atomicAdd(&sumsq[c], q);
    }
}

__global__ void bn_finalize(const double* __restrict__ sum, const double* __restrict__ sumsq,
                            const float* __restrict__ g, const float* __restrict__ b,
                            double invM, int Ch,
                            double* __restrict__ scale, double* __restrict__ shift) {
    int c = blockIdx.x * 256 + threadIdx.x;
    if (c >= Ch) return;
    double m   = sum[c] * invM;
    double var = sumsq[c] * invM - m * m;
    double sc  = (double)g[c] / sqrt(var + 1e-5);
    scale[c] = sc;
    shift[c] = (double)b[c] - m * sc;
}

// ===========================================================================
// LIF kernels -> bit-packed spikes via ballot. tau=2, vth=1, hard reset.
// ===========================================================================
__device__ __forceinline__ void lif2(double x0, double x1, bool& s0, bool& s1) {
    double v = x0 * 0.5;
    s0 = (v >= 1.0);
    v = s0 ? 0.0 : v;
    v = v + (x1 - v) * 0.5;
    s1 = (v >= 1.0);
}

// from h (double, [2,N,512]) -> bits [2, N*8 words]
__global__ __launch_bounds__(256)
void lif_bits_d(const double* __restrict__ H, uint64_t* __restrict__ S) {
    int i = blockIdx.x * 256 + threadIdx.x;   // i < N*512 (multiple of 256)
    bool s0, s1;
    lif2(H[i], H[(size_t)i + ND], s0, s1);
    uint64_t b0 = __ballot(s0), b1 = __ballot(s1);
    if ((threadIdx.x & 63) == 0) {
        int widx = i >> 6;
        S[widx] = b0;
        S[widx + N_NODES * 8] = b1;
    }
}

// from attention O (float, exact) -> bits
__global__ __launch_bounds__(256)
void lif_bits_f(const float* __restrict__ O, uint64_t* __restrict__ S) {
    int i = blockIdx.x * 256 + threadIdx.x;
    bool s0, s1;
    lif2((double)O[i], (double)O[(size_t)i + ND], s0, s1);
    uint64_t b0 = __ballot(s0), b1 = __ballot(s1);
    if ((threadIdx.x & 63) == 0) {
        int widx = i >> 6;
        S[widx] = b0;
        S[widx + N_NODES * 8] = b1;
    }
}

// BN-apply + LIF on a 256-ch double chunk X [2, N, 256] -> bits at chOff.
__global__ __launch_bounds__(256)
void bn_lif_bits(const double* __restrict__ X, const double* __restrict__ scale,
                 const double* __restrict__ shift, uint64_t* __restrict__ S,
                 int osWords, int chOffWords) {
    int i = blockIdx.x * 256 + threadIdx.x;   // i < N*256
    int n = i >> 8, c = i & 255;
    double sc = scale[c], sh = shift[c];
    bool s0, s1;
    lif2((double)X[i] * sc + sh, (double)X[(size_t)i + (size_t)N_NODES * 256] * sc + sh, s0, s1);
    uint64_t b0 = __ballot(s0), b1 = __ballot(s1);
    if ((threadIdx.x & 63) == 0) {
        int widx = n * osWords + chOffWords + ((c & 255) >> 6);
        S[widx] = b0;
        S[widx + N_NODES * osWords] = b1;
    }
}

// h += bn(X) for a 256-ch chunk.
__global__ __launch_bounds__(256)
void bn_add_d(const double* __restrict__ X, const double* __restrict__ scale,
              const double* __restrict__ shift, double* __restrict__ H, int chOff) {
    int i = blockIdx.x * 256 + threadIdx.x;   // i < N*256
    int n = i >> 8, c = i & 255;
    double sc = scale[c], sh = shift[c];
    size_t hi = (size_t)n * 512 + chOff + c;
    H[hi] += (double)X[i] * sc + sh;
    H[hi + ND] += (double)X[(size_t)i + (size_t)N_NODES * 256] * sc + sh;
}

// LayerNorm(512)+ReLU on fc0 output (double [N,512]); write both t-slices of h.
__global__ __launch_bounds__(256)
void ln_relu_d(const double* __restrict__ X, const float* __restrict__ g,
               const float* __restrict__ b, double* __restrict__ H) {
    int n = blockIdx.x;
    const double* x = X + (size_t)n * 512;
    int c0 = threadIdx.x, c1 = threadIdx.x + 256;
    double v0 = x[c0], v1 = x[c1];
    __shared__ double ls[256], lq[256];
    ls[threadIdx.x] = v0 + v1;
    lq[threadIdx.x] = v0 * v0 + v1 * v1;
    __syncthreads();
    for (int off = 128; off > 0; off >>= 1) {
        if (threadIdx.x < off) {
            ls[threadIdx.x] += ls[threadIdx.x + off];
            lq[threadIdx.x] += lq[threadIdx.x + off];
        }
        __syncthreads();
    }
    double m    = ls[0] * (1.0 / 512);
    double var  = lq[0] * (1.0 / 512) - m * m;
    double rstd = 1.0 / sqrt(var + 1e-5);
    double o0 = (v0 - m) * rstd * (double)g[c0] + (double)b[c0];
    double o1 = (v1 - m) * rstd * (double)g[c1] + (double)b[c1];
    o0 = o0 > 0.0 ? o0 : 0.0;
    o1 = o1 > 0.0 ? o1 : 0.0;
    double* h0 = H + (size_t)n * 512;
    h0[c0] = o0; h0[c1] = o1;
    h0[ND + c0] = o0; h0[ND + c1] = o1;
}

// ===========================================================================
// Attention on bit spikes (integer-exact in fp32).
// ===========================================================================
__global__ __launch_bounds__(256)
void kv_bits(const uint64_t* __restrict__ Kb, const uint64_t* __restrict__ Vb,
             float* __restrict__ KV, int nPerBlock) {
    const int th = blockIdx.x;          // t*8 + h
    const int t = th >> 3, h = th & 7;
    const int nbase = blockIdx.y * nPerBlock;
    const int e = threadIdx.x & 63, dg = threadIdx.x >> 6;
    float acc[16];
#pragma unroll
    for (int i = 0; i < 16; i++) acc[i] = 0.f;
    __shared__ float ks[8][64], vs[8][64];
    const size_t wbase = (size_t)t * N_NODES * 8 + h;
    for (int n0 = 0; n0 < nPerBlock; n0 += 8) {
        for (int idx = threadIdx.x; idx < 8 * 128; idx += 256) {
            int r = idx >> 7, c = idx & 127;
            size_t wi = wbase + (size_t)(nbase + n0 + r) * 8;
            if (c < 64) ks[r][c] = (float)((Kb[wi] >> c) & 1ull);
            else        vs[r][c - 64] = (float)((Vb[wi] >> (c - 64)) & 1ull);
        }
        __syncthreads();
#pragma unroll
        for (int r = 0; r < 8; ++r) {
            float ve = vs[r][e];
#pragma unroll
            for (int i = 0; i < 16; ++i) acc[i] += ks[r][dg * 16 + i] * ve;
        }
        __syncthreads();
    }
    float* kvp = KV + (size_t)th * 4096;
    for (int i = 0; i < 16; ++i)
        atomicAdd(&kvp[(dg * 16 + i) * 64 + e], acc[i]);
}

__global__ __launch_bounds__(256)
void o_bits(const uint64_t* __restrict__ Qb, const float* __restrict__ KV,
            float* __restrict__ O) {
    const int th = blockIdx.y;
    const int t = th >> 3, h = th & 7;
    const int nb = blockIdx.x;
    __shared__ float kvs[64][64];
    __shared__ float qs[64][65];
    const float* kvp = KV + (size_t)th * 4096;
    for (int idx = threadIdx.x; idx < 4096; idx += 256)
        kvs[idx >> 6][idx & 63] = kvp[idx];
    const size_t wbase = ((size_t)t * N_NODES + (size_t)nb * 64) * 8 + h;
    for (int idx = threadIdx.x; idx < 4096; idx += 256) {
        int r = idx >> 6, c = idx & 63;
        qs[r][c] = (float)((Qb[wbase + (size_t)r * 8] >> c) & 1ull);
    }
    __syncthreads();
    const int e = threadIdx.x & 63, rg = threadIdx.x >> 6;
    float acc[16];
#pragma unroll
    for (int i = 0; i < 16; i++) acc[i] = 0.f;
    for (int d = 0; d < 64; ++d) {
        float kv = kvs[d][e];
#pragma unroll
        for (int i = 0; i < 16; ++i) acc[i] += qs[rg * 16 + i][d] * kv;
    }
    const size_t obase = ((size_t)t * N_NODES + (size_t)nb * 64) * 512 + (size_t)h * 64;
    for (int i = 0; i < 16; ++i)
        O[obase + (size_t)(rg * 16 + i) * 512 + e] = acc[i] * 0.125f;
}

// ===========================================================================
// GNN branch (fp32; ReLU-only nonlinearity -> no cascade risk)
// ===========================================================================
__global__ __launch_bounds__(256)
void deg_kernel(const int* __restrict__ col, float* __restrict__ deg, int E) {
    int e = blockIdx.x * 256 + threadIdx.x;
    if (e < E) atomicAdd(&deg[col[e]], 1.0f);
}

__global__ __launch_bounds__(256)
void dinv_kernel(float* __restrict__ deg, int n) {
    int i = blockIdx.x * 256 + threadIdx.x;
    if (i < n) {
        double d = (double)deg[i];
        deg[i] = d > 0.0 ? (float)(1.0 / sqrt(d)) : 0.f;
    }
}

__global__ __launch_bounds__(256)
void agg_kernel(const float* __restrict__ G, const int* __restrict__ row,
                const int* __restrict__ col, const float* __restrict__ dinv,
                float* __restrict__ out, int E) {
    int idx = blockIdx.x * 256 + threadIdx.x;
    int e = idx >> 6, c = idx & 63;
    if (e >= E || c >= C_OUT) return;
    int r = row[e], cl = col[e];
    float val = dinv[cl] * dinv[r];
    atomicAdd(&out[(size_t)cl * C_OUT + c], val * G[(size_t)r * C_OUT + c]);
}

__global__ __launch_bounds__(256)
void bn_relu_add_f(const float* __restrict__ X, const double* __restrict__ scale,
                   const double* __restrict__ shift, const float* __restrict__ add,
                   float* __restrict__ out, int NC, int Ch) {
    int i = blockIdx.x * 256 + threadIdx.x;
    if (i >= NC) return;
    int c = i % Ch;
    double v = (double)X[i] * scale[c] + shift[c];
    v = v > 0.0 ? v : 0.0;
    if (add) v += (double)add[i];
    out[i] = (float)v;
}

__global__ __launch_bounds__(256)
void mix_kernel(const float* __restrict__ G, const float* __restrict__ Y,
                float* __restrict__ P, int NC) {
    int i = blockIdx.x * 256 + threadIdx.x;
    if (i >= NC) return;
    double y = 0.5 * ((double)Y[i] + (double)Y[(size_t)i + NC]);
    P[i] = (float)(0.8 * (double)G[i] + 0.2 * y);
}

__global__ __launch_bounds__(256)
void final_fc_kernel(const float* __restrict__ A, const float* __restrict__ W,
                     const float* __restrict__ bias, float* __restrict__ out) {
    __shared__ float Ws[40][40];
    for (int idx = threadIdx.x; idx < 1600; idx += 256)
        Ws[idx / 40][idx % 40] = W[idx];
    __syncthreads();
    int i = blockIdx.x * 256 + threadIdx.x;
    if (i >= N_NODES * C_OUT) return;
    int n = i / 40, c = i - n * 40;
    const float* a = A + (size_t)n * 40;
    double acc = (double)bias[c];
#pragma unroll 8
    for (int k = 0; k < 40; ++k) acc += (double)a[k] * (double)Ws[k][c];
    out[i] = (float)acc;
}

// ===========================================================================
// Host orchestration
// ===========================================================================
static inline dim3 grid1(long n) { return dim3((unsigned)((n + 255) / 256)); }

static void bn_stats_d(hipStream_t st, const double* X, int M, int Ch,
                       const float* g, const float* b,
                       double* dsum, double* scale, double* shift) {
    hipMemsetAsync(dsum, 0, 2 * 1024 * sizeof(double), st);
    dim3 gs((Ch + 63) / 64, (M + 511) / 512);
    hipLaunchKernelGGL(col_stats<double>, gs, dim3(256), 0, st, X, M, Ch, 512, dsum, dsum + 1024);
    hipLaunchKernelGGL(bn_finalize, dim3((Ch + 255) / 256), dim3(256), 0, st,
                       dsum, dsum + 1024, g, b, 1.0 / (double)M, Ch, scale, shift);
}

static void bn_stats_f(hipStream_t st, const float* X, int M, int Ch,
                       const float* g, const float* b,
                       double* dsum, double* scale, double* shift) {
    hipMemsetAsync(dsum, 0, 2 * 1024 * sizeof(double), st);
    dim3 gs((Ch + 63) / 64, (M + 511) / 512);
    hipLaunchKernelGGL(col_stats<float>, gs, dim3(256), 0, st, X, M, Ch, 512, dsum, dsum + 1024);
    hipLaunchKernelGGL(bn_finalize, dim3((Ch + 255) / 256), dim3(256), 0, st,
                       dsum, dsum + 1024, g, b, 1.0 / (double)M, Ch, scale, shift);
}

extern "C" void kernel_launch(void* const* d_in, const int* in_sizes, int n_in,
                              void* d_out, int out_size, void* d_ws, size_t ws_size,
                              hipStream_t stream) {
    const float* x      = (const float*)d_in[0];
    const float* fc0_w  = (const float*)d_in[1];
    const float* fc0_b  = (const float*)d_in[2];
    const float* ln_g   = (const float*)d_in[3];
    const float* ln_b   = (const float*)d_in[4];
    const float* wq     = (const float*)d_in[5];
    const float* wk     = (const float*)d_in[6];
    const float* wv     = (const float*)d_in[7];
    const float* wo     = (const float*)d_in[8];
    const float* bnq_g  = (const float*)d_in[9];
    const float* bnq_b  = (const float*)d_in[10];
    const float* bnk_g  = (const float*)d_in[11];
    const float* bnk_b  = (const float*)d_in[12];
    const float* bnv_g  = (const float*)d_in[13];
    const float* bnv_b  = (const float*)d_in[14];
    const float* bno_g  = (const float*)d_in[15];
    const float* bno_b  = (const float*)d_in[16];
    const float* w1     = (const float*)d_in[17];
    const float* bn1_g  = (const float*)d_in[18];
    const float* bn1_b  = (const float*)d_in[19];
    const float* w2     = (const float*)d_in[20];
    const float* bn2_g  = (const float*)d_in[21];
    const float* bn2_b  = (const float*)d_in[22];
    const float* head_w = (const float*)d_in[23];
    const float* head_b = (const float*)d_in[24];
    const float* gfc_w  = (const float*)d_in[25];
    const float* gfc_b  = (const float*)d_in[26];
    const float* gbn0_g = (const float*)d_in[27];
    const float* gbn0_b = (const float*)d_in[28];
    const float* gconv_w= (const float*)d_in[29];
    const float* gconv_b= (const float*)d_in[30];
    const float* gbn_g  = (const float*)d_in[31];
    const float* gbn_b  = (const float*)d_in[32];
    const float* fc_w   = (const float*)d_in[33];
    const float* fc_b   = (const float*)d_in[34];
    const int*   edge   = (const int*)d_in[35];

    const int E = in_sizes[35] / 2;
    const int* erow = edge;
    const int* ecol = edge + E;
    const int NC = N_NODES * C_OUT;

    // ---- workspace layout (~227 MiB) ----
    uint8_t* wsbase = (uint8_t*)d_ws;
    size_t off = 0;
    auto alloc = [&](size_t bytes, size_t align) -> void* {
        off = (off + align - 1) & ~(align - 1);
        void* p = wsbase + off;
        off += bytes;
        return p;
    };
    double*   dsum   = (double*)alloc(2 * 1024 * sizeof(double), 256);
    double*   scale  = (double*)alloc(1024 * sizeof(double), 256);
    double*   shift  = (double*)alloc(1024 * sizeof(double), 256);
    double*   h_buf  = (double*)alloc((size_t)2 * ND * sizeof(double), 256);   // 134 MB
    double*   Pd     = (double*)alloc((size_t)M2 * CW * sizeof(double), 256);  // 67 MB
    float*    O32    = (float*)Pd;  // alias: attention output (exact fp32), same 67 MB
    uint64_t* s_bits = (uint64_t*)alloc((size_t)2 * N_NODES * 8 * 8, 256);     // 2.1 MB
    uint64_t* q_bits = (uint64_t*)alloc((size_t)2 * N_NODES * 8 * 8, 256);
    uint64_t* k_bits = (uint64_t*)alloc((size_t)2 * N_NODES * 8 * 8, 256);
    uint64_t* v_bits = (uint64_t*)alloc((size_t)2 * N_NODES * 8 * 8, 256);
    uint64_t* m_bits = (uint64_t*)alloc((size_t)2 * N_NODES * 16 * 8, 256);    // 4.2 MB
    float*    ybuf   = (float*)alloc((size_t)2 * NC * sizeof(float), 256);
    float*    g0     = (float*)alloc((size_t)NC * sizeof(float), 256);
    float*    gg     = (float*)alloc((size_t)NC * sizeof(float), 256);
    float*    ag     = (float*)alloc((size_t)NC * sizeof(float), 256);
    float*    kvb    = (float*)alloc((size_t)65536 * sizeof(float), 256);
    float*    deg    = (float*)alloc((size_t)N_NODES * sizeof(float), 256);
    if (off > ws_size) return;

    const dim3 blk(256);
    const dim3 gLIF((unsigned)(ND / 256));        // N*512/256
    const dim3 gCHK((unsigned)(N_NODES));         // N*256/256

    // ===== transformer branch (all-double spiking path) =====
    // fc0: x @ fc0_w + b -> Pd[N,512] (double), then LN+ReLU -> h (both t)
    hipLaunchKernelGGL(gemm_f32d, dim3(8, N_NODES / 64), blk, 0, stream,
                       x, 512, fc0_w, 512, fc0_b, Pd, 512, N_NODES, 512, 512);
    hipLaunchKernelGGL(ln_relu_d, dim3(N_NODES), blk, 0, stream, Pd, ln_g, ln_b, h_buf);

    for (int l = 0; l < 4; ++l) {
        const float* wq_l = wq + (size_t)l * 512 * 512;
        const float* wk_l = wk + (size_t)l * 512 * 512;
        const float* wv_l = wv + (size_t)l * 512 * 512;
        const float* wo_l = wo + (size_t)l * 512 * 512;
        const float* w1_l = w1 + (size_t)l * 512 * 1024;
        const float* w2_l = w2 + (size_t)l * 1024 * 512;

        hipLaunchKernelGGL(lif_bits_d, gLIF, blk, 0, stream, h_buf, s_bits);

        uint64_t* qkvb[3] = {q_bits, k_bits, v_bits};
        const float* wmat[3] = {wq_l, wk_l, wv_l};
        const float* gmat[3] = {bnq_g + l * 512, bnk_g + l * 512, bnv_g + l * 512};
        const float* bmat[3] = {bnq_b + l * 512, bnk_b + l * 512, bnv_b + l * 512};
        for (int j = 0; j < 3; ++j) {
            for (int c0 = 0; c0 < 512; c0 += CW) {
                hipLaunchKernelGGL(gemm_bits<double>, dim3(CW / 64, M2 / 64), blk, 0, stream,
                                   (const uint32_t*)s_bits, 16, wmat[j], 512, c0,
                                   (const float*)nullptr, Pd, CW, M2, CW, 512);
                bn_stats_d(stream, Pd, M2, CW, gmat[j] + c0, bmat[j] + c0, dsum, scale, shift);
                hipLaunchKernelGGL(bn_lif_bits, gCHK, blk, 0, stream,
                                   Pd, scale, shift, qkvb[j], 8, c0 / 64);
            }
        }

        // attention (exact): kv, then o -> O32 (aliases Pd; Pd dead here)
        hipMemsetAsync(kvb, 0, 65536 * sizeof(float), stream);
        hipLaunchKernelGGL(kv_bits, dim3(16, 16), blk, 0, stream, k_bits, v_bits, kvb, 1024);
        hipLaunchKernelGGL(o_bits, dim3(N_NODES / 64, 16), blk, 0, stream, q_bits, kvb, O32);
        hipLaunchKernelGGL(lif_bits_f, gLIF, blk, 0, stream, O32, s_bits);

        // h += bn(lif(o) @ wo)
        for (int c0 = 0; c0 < 512; c0 += CW) {
            hipLaunchKernelGGL(gemm_bits<double>, dim3(CW / 64, M2 / 64), blk, 0, stream,
                               (const uint32_t*)s_bits, 16, wo_l, 512, c0,
                               (const float*)nullptr, Pd, CW, M2, CW, 512);
            bn_stats_d(stream, Pd, M2, CW, bno_g + l * 512 + c0, bno_b + l * 512 + c0, dsum, scale, shift);
            hipLaunchKernelGGL(bn_add_d, gCHK, blk, 0, stream, Pd, scale, shift, h_buf, c0);
        }

        // MLP: m = lif(bn1(lif(h) @ w1)) in 4 chunks of 256
        hipLaunchKernelGGL(lif_bits_d, gLIF, blk, 0, stream, h_buf, s_bits);
        for (int c0 = 0; c0 < 1024; c0 += CW) {
            hipLaunchKernelGGL(gemm_bits<double>, dim3(CW / 64, M2 / 64), blk, 0, stream,
                               (const uint32_t*)s_bits, 16, w1_l, 1024, c0,
                               (const float*)nullptr, Pd, CW, M2, CW, 512);
            bn_stats_d(stream, Pd, M2, CW, bn1_g + l * 1024 + c0, bn1_b + l * 1024 + c0, dsum, scale, shift);
            hipLaunchKernelGGL(bn_lif_bits, gCHK, blk, 0, stream,
                               Pd, scale, shift, m_bits, 16, c0 / 64);
        }
        // h += bn2(m @ w2)
        for (int c0 = 0; c0 < 512; c0 += CW) {
            hipLaunchKernelGGL(gemm_bits<double>, dim3(CW / 64, M2 / 64), blk, 0, stream,
                               (const uint32_t*)m_bits, 32, w2_l, 512, c0,
                               (const float*)nullptr, Pd, CW, M2, CW, 1024);
            bn_stats_d(stream, Pd, M2, CW, bn2_g + l * 512 + c0, bn2_b + l * 512 + c0, dsum, scale, shift);
            hipLaunchKernelGGL(bn_add_d, gCHK, blk, 0, stream, Pd, scale, shift, h_buf, c0);
        }
    }

    // head: y = lif(h) @ head_w + head_b (fp32 out; no thresholds after)
    hipLaunchKernelGGL(lif_bits_d, gLIF, blk, 0, stream, h_buf, s_bits);
    hipLaunchKernelGGL(gemm_bits<float>, dim3(1, M2 / 64), blk, 0, stream,
                       (const uint32_t*)s_bits, 16, head_w, 40, 0, head_b, ybuf, 40, M2, 40, 512);

    // ===== GNN branch (fp32) =====
    hipLaunchKernelGGL(gemm_f32, dim3(1, N_NODES / 64), blk, 0, stream,
                       x, 512, gfc_w, 40, gfc_b, ag, 40, N_NODES, 40, 512);
    bn_stats_f(stream, ag, N_NODES, 40, gbn0_g, gbn0_b, dsum, scale, shift);
    hipLaunchKernelGGL(bn_relu_add_f, grid1(NC), blk, 0, stream,
                       ag, scale, shift, (const float*)nullptr, g0, NC, 40);

    hipMemsetAsync(deg, 0, N_NODES * sizeof(float), stream);
    hipLaunchKernelGGL(deg_kernel, grid1(E), blk, 0, stream, ecol, deg, E);
    hipLaunchKernelGGL(dinv_kernel, grid1(N_NODES), blk, 0, stream, deg, N_NODES);

    const float* gsrc = g0;
    for (int i = 0; i < 2; ++i) {
        hipMemsetAsync(ag, 0, (size_t)NC * sizeof(float), stream);
        hipLaunchKernelGGL(agg_kernel, grid1((long)E * 64), blk, 0, stream,
                           gsrc, erow, ecol, deg, ag, E);
        hipLaunchKernelGGL(gemm_f32, dim3(1, N_NODES / 64), blk, 0, stream,
                           ag, 40, gconv_w + (size_t)i * 40 * 40, 40, gconv_b + i * 40,
                           gg, 40, N_NODES, 40, 40);
        bn_stats_f(stream, gg, N_NODES, 40, gbn_g + i * 40, gbn_b + i * 40, dsum, scale, shift);
        hipLaunchKernelGGL(bn_relu_add_f, grid1(NC), blk, 0, stream,
                           gg, scale, shift, g0, gg, NC, 40);
        gsrc = gg;
    }

    // out = (0.8*g + 0.2*mean_t(y)) @ fc_w + fc_b
    hipLaunchKernelGGL(mix_kernel, grid1(NC), blk, 0, stream, gg, ybuf, ag, NC);
    hipLaunchKernelGGL(final_fc_kernel, grid1((long)N_NODES * C_OUT), blk, 0, stream,
                       ag, fc_w, fc_b, (float*)d_out);
}